// Round 22
// baseline (34.399 us; speedup 1.0000x reference)
//
#include <hip/hip_runtime.h>

// Depthwise 7x7 'same' conv, fp32 in/out. B=16, C=256, H=W=64.
// R21 (31.6us best: global_load_lds DMA staging -> LDS, 4x4-lane dot2
// compute) + WITHIN-BLOCK DOUBLE-BUFFERED STAGING:
//   block = 2 planes, lds[2][4096]. Stage A (4 loads/wave), stage B
//   (4 more). Counted wait vmcnt(4) -> A's loads done (loads return in
//   order; no stores issued yet so the count is pure-load, fixing R6's
//   mistake). RAW s_barrier (NOT __syncthreads, which force-drains
//   vmcnt(0) and would kill the overlap). compute A. vmcnt(0) + barrier
//   (B landed under compute A). compute B.
// Exposed stage-waits per plane halve; occupancy cost: 32 KB LDS ->
// 5 blocks/CU (20 waves/CU vs R21's 32).

typedef _Float16 v2h __attribute__((ext_vector_type(2)));

static __device__ __forceinline__ v2h pack2(float a, float b) {
    return __builtin_bit_cast(v2h, __builtin_amdgcn_cvt_pkrtz(a, b));
}

__global__ void dwconv7x7_glds2(const float* __restrict__ x,
                                const float* __restrict__ weight,
                                const float* __restrict__ bias,
                                float* __restrict__ out) {
    __shared__ float lds[2][4096];

    const int tid   = threadIdx.x;     // 0..255
    const int lane  = tid & 63;
    const int wid   = tid >> 6;        // wave 0..3
    const int pbase = blockIdx.x * 2;  // planes pbase, pbase+1

    // ---- stage BOTH planes up front (VGPR-free async DMA) ----
    // wave w stages chunks 4w..4w+3 of each plane (1 KB chunks).
#pragma unroll
    for (int ph = 0; ph < 2; ++ph) {
        const float* xp = x + (size_t)(pbase + ph) * 4096;
        auto* gsrc  = (const __attribute__((address_space(1))) float*)xp;
        auto* lbase = (__attribute__((address_space(3))) float*)lds[ph];
#pragma unroll
        for (int k = 0; k < 4; ++k) {
            const int chunk = wid * 4 + k;           // wave-uniform
            __builtin_amdgcn_global_load_lds(
                (const __attribute__((address_space(1))) void*)
                    (gsrc + chunk * 256 + lane * 4),
                (__attribute__((address_space(3))) void*)(lbase + chunk * 256),
                16, 0, 0);
        }
    }

    // ---- compute geometry (same for both phases) ----
    const int tx = lane & 15;            // 16 tiles across width
    const int sy = lane >> 4;            // 4 strips per wave
    const int wb = tx * 4;               // output col base
    const int hb = wid * 16 + sy * 4;    // output row base
    const int offm = (tx > 0)  ? (wb - 4) : wb;   // clamped aligned left
    const int offp = (tx < 15) ? (wb + 4) : wb;   // clamped aligned right

#pragma unroll 1
    for (int ph = 0; ph < 2; ++ph) {
        const int plane = pbase + ph;
        const int c     = plane & 255;   // block-uniform

        // weights for this phase (uniform -> scalar path). Even if the
        // compiler emits vector loads here, they are NEWER than the
        // stage loads, so vmcnt(4) below still guarantees A's 4 oldest.
        const float* wp = weight + c * 49;
        float wk[49];
#pragma unroll
        for (int k = 0; k < 49; ++k) wk[k] = wp[k];
        const float bv = bias[c];

        v2h  W[7][3];
        float w6[7];
#pragma unroll
        for (int kr = 0; kr < 7; ++kr) {
#pragma unroll
            for (int t = 0; t < 3; ++t) {
                v2h p = pack2(wk[kr * 7 + 2 * t], wk[kr * 7 + 2 * t + 1]);
                int b = __builtin_amdgcn_readfirstlane(__builtin_bit_cast(int, p));
                W[kr][t] = __builtin_bit_cast(v2h, b);
            }
            w6[kr] = wk[kr * 7 + 6];
        }

        // wait for THIS phase's staged plane; keep the other in flight.
        if (ph == 0) {
            asm volatile("s_waitcnt vmcnt(4)" ::: "memory");
        } else {
            asm volatile("s_waitcnt vmcnt(0)" ::: "memory");
        }
        __builtin_amdgcn_sched_barrier(0);
        __builtin_amdgcn_s_barrier();    // raw barrier: no forced drain

        const float* ldp = lds[ph];

        float acc[4][4];
#pragma unroll
        for (int i = 0; i < 4; ++i)
#pragma unroll
            for (int j = 0; j < 4; ++j) acc[i][j] = 0.f;

        // Stream input rows hb-3 .. hb+6 (10 steps) from LDS.
#pragma unroll
        for (int j = 0; j < 10; ++j) {
            const int r  = hb - 3 + j;
            const int rc = min(max(r, 0), 63);
            const float* rp = &ldp[rc * 64];
            const bool mrow = (r >= 0) && (r < 64);
            const bool mm = mrow && (tx > 0);
            const bool mp = mrow && (tx < 15);

            float4 qm = *reinterpret_cast<const float4*>(rp + offm);
            float4 q0 = *reinterpret_cast<const float4*>(rp + wb);
            float4 qp = *reinterpret_cast<const float4*>(rp + offp);

            // f[i] = x[r][wb-3+i], i = 0..9 (masked to zero outside)
            float f[10];
            f[0] = mm   ? qm.y : 0.f;
            f[1] = mm   ? qm.z : 0.f;
            f[2] = mm   ? qm.w : 0.f;
            f[3] = mrow ? q0.x : 0.f;
            f[4] = mrow ? q0.y : 0.f;
            f[5] = mrow ? q0.z : 0.f;
            f[6] = mrow ? q0.w : 0.f;
            f[7] = mp   ? qp.x : 0.f;
            f[8] = mp   ? qp.y : 0.f;
            f[9] = mp   ? qp.z : 0.f;

            // sliding half2 pairs: pk[t] = (f[t], f[t+1])
            v2h pk[8];
#pragma unroll
            for (int t = 0; t < 8; ++t) pk[t] = pack2(f[t], f[t + 1]);

            // output row oi (kr = j - oi), col wb+jj: taps -> f[jj+kc]
#pragma unroll
            for (int oi = 0; oi < 4; ++oi) {
                const int kr = j - oi;
                if (kr >= 0 && kr < 7) {
#pragma unroll
                    for (int jj = 0; jj < 4; ++jj) {
                        float a = fmaf(f[jj + 6], w6[kr], acc[oi][jj]);
                        a = __builtin_amdgcn_fdot2(pk[jj + 4], W[kr][2], a, false);
                        a = __builtin_amdgcn_fdot2(pk[jj + 2], W[kr][1], a, false);
                        a = __builtin_amdgcn_fdot2(pk[jj],     W[kr][0], a, false);
                        acc[oi][jj] = a;
                    }
                }
            }
        }

        // ---- write 4 rows x float4, plus bias ----
        float* op = out + (size_t)plane * 4096 + (size_t)hb * 64 + wb;
#pragma unroll
        for (int oi = 0; oi < 4; ++oi) {
            float4 v;
            v.x = acc[oi][0] + bv;
            v.y = acc[oi][1] + bv;
            v.z = acc[oi][2] + bv;
            v.w = acc[oi][3] + bv;
            *reinterpret_cast<float4*>(op + oi * 64) = v;
        }
    }
}

extern "C" void kernel_launch(void* const* d_in, const int* in_sizes, int n_in,
                              void* d_out, int out_size, void* d_ws, size_t ws_size,
                              hipStream_t stream) {
    const float* x      = (const float*)d_in[0];
    const float* weight = (const float*)d_in[1];
    const float* bias   = (const float*)d_in[2];
    float* out          = (float*)d_out;
    (void)in_sizes; (void)n_in; (void)out_size; (void)d_ws; (void)ws_size;

    dim3 grid(2048);   // one block per 2 planes
    dim3 block(256);
    dwconv7x7_glds2<<<grid, block, 0, stream>>>(x, weight, bias, out);
}